// Round 15
// baseline (674.757 us; speedup 1.0000x reference)
//
#include <hip/hip_runtime.h>
#include <hip/hip_bf16.h>

#define Bn 64
#define Tn 512
#define En 128
#define Hn 64
#define Gn 256   // 4*H
#define Cn 20

__device__ __forceinline__ float sigf(float x)      { return 1.f/(1.f+__expf(-x)); }
__device__ __forceinline__ float tanhfast(float x)  { return 2.f/(1.f+__expf(-2.f*x)) - 1.f; }

// ---------------------------------------------------------------------------
// Kernel A: Z0[b*T+t][j] = (word_emb[ids[b,t]] + pos_emb[t]) @ Wx_b0 + b_b0
// ---------------------------------------------------------------------------
__global__ __launch_bounds__(256, 1) void emb_proj_kernel(
    const int* __restrict__ x, const float* __restrict__ word_emb,
    const float* __restrict__ pos_emb, const float* __restrict__ wx,
    const float* __restrict__ bias, float* __restrict__ z0)
{
  __shared__ float emb[64][En];     // 32 KB
  __shared__ float wxl[32][Gn];     // 32 KB
  const int tid  = threadIdx.x;
  const int row0 = blockIdx.x * 64;

  #pragma unroll
  for (int it = 0; it < 8; ++it) {
    int idx = it*256 + tid;
    int rr  = idx >> 5;
    int e4  = (idx & 31) << 2;
    int r   = row0 + rr;
    int b   = r >> 9;
    int t   = r & (Tn-1);
    int id  = x[b*3*Tn + t];
    float4 we = *reinterpret_cast<const float4*>(&word_emb[(size_t)id*En + e4]);
    float4 pe = *reinterpret_cast<const float4*>(&pos_emb[(size_t)t*En + e4]);
    *reinterpret_cast<float4*>(&emb[rr][e4]) =
        make_float4(we.x+pe.x, we.y+pe.y, we.z+pe.z, we.w+pe.w);
  }

  const int jc = tid & 63;
  const int rg = tid >> 6;
  float acc[16][4];
  float4 bb = *reinterpret_cast<const float4*>(&bias[jc*4]);
  #pragma unroll
  for (int r = 0; r < 16; ++r) { acc[r][0]=bb.x; acc[r][1]=bb.y; acc[r][2]=bb.z; acc[r][3]=bb.w; }

  for (int ec = 0; ec < 4; ++ec) {
    __syncthreads();
    #pragma unroll
    for (int it = 0; it < 8; ++it) {
      int idx = it*256 + tid;
      int ee  = idx >> 6;
      int j4  = (idx & 63) << 2;
      *reinterpret_cast<float4*>(&wxl[ee][j4]) =
          *reinterpret_cast<const float4*>(&wx[(size_t)(ec*32+ee)*Gn + j4]);
    }
    __syncthreads();
    for (int ee = 0; ee < 32; ++ee) {
      float4 w = *reinterpret_cast<const float4*>(&wxl[ee][jc*4]);
      #pragma unroll
      for (int r = 0; r < 16; ++r) {
        float xv = emb[rg*16+r][ec*32+ee];
        acc[r][0] = fmaf(xv, w.x, acc[r][0]);
        acc[r][1] = fmaf(xv, w.y, acc[r][1]);
        acc[r][2] = fmaf(xv, w.z, acc[r][2]);
        acc[r][3] = fmaf(xv, w.w, acc[r][3]);
      }
    }
  }
  #pragma unroll
  for (int r = 0; r < 16; ++r) {
    size_t row = (size_t)row0 + rg*16 + r;
    *reinterpret_cast<float4*>(&z0[row*Gn + jc*4]) =
        make_float4(acc[r][0], acc[r][1], acc[r][2], acc[r][3]);
  }
}

// ---------------------------------------------------------------------------
// Kernel A2: ZX1[b*T+t][j] = hb0[b,t,:] @ Wx_b1 + b_b1
// ---------------------------------------------------------------------------
__global__ __launch_bounds__(256, 1) void zx1_gemm_kernel(
    const float* __restrict__ hb0, const float* __restrict__ wx,
    const float* __restrict__ bias, float* __restrict__ zx1)
{
  __shared__ float xl[64][Hn];
  __shared__ float wl[32][Gn];
  const int tid  = threadIdx.x;
  const int row0 = blockIdx.x * 64;

  #pragma unroll
  for (int it = 0; it < 4; ++it) {
    int idx = it*256 + tid;
    int rr  = idx >> 4;
    int e4  = (idx & 15) << 2;
    *reinterpret_cast<float4*>(&xl[rr][e4]) =
        *reinterpret_cast<const float4*>(&hb0[((size_t)row0+rr)*Hn + e4]);
  }

  const int jc = tid & 63;
  const int rg = tid >> 6;
  float acc[16][4];
  float4 bb = *reinterpret_cast<const float4*>(&bias[jc*4]);
  #pragma unroll
  for (int r = 0; r < 16; ++r) { acc[r][0]=bb.x; acc[r][1]=bb.y; acc[r][2]=bb.z; acc[r][3]=bb.w; }

  for (int kc = 0; kc < 2; ++kc) {
    __syncthreads();
    #pragma unroll
    for (int it = 0; it < 8; ++it) {
      int idx = it*256 + tid;
      int kk  = idx >> 6;
      int j4  = (idx & 63) << 2;
      *reinterpret_cast<float4*>(&wl[kk][j4]) =
          *reinterpret_cast<const float4*>(&wx[(size_t)(kc*32+kk)*Gn + j4]);
    }
    __syncthreads();
    for (int kk = 0; kk < 32; ++kk) {
      float4 w = *reinterpret_cast<const float4*>(&wl[kk][jc*4]);
      #pragma unroll
      for (int r = 0; r < 16; ++r) {
        float xv = xl[rg*16+r][kc*32+kk];
        acc[r][0] = fmaf(xv, w.x, acc[r][0]);
        acc[r][1] = fmaf(xv, w.y, acc[r][1]);
        acc[r][2] = fmaf(xv, w.z, acc[r][2]);
        acc[r][3] = fmaf(xv, w.w, acc[r][3]);
      }
    }
  }
  #pragma unroll
  for (int r = 0; r < 16; ++r) {
    size_t row = (size_t)row0 + rg*16 + r;
    *reinterpret_cast<float4*>(&zx1[row*Gn + jc*4]) =
        make_float4(acc[r][0], acc[r][1], acc[r][2], acc[r][3]);
  }
}

// ---------------------------------------------------------------------------
// Recurrence: 256 threads / 4 waves per batch element; thread tid owns gate
// column tid (wave wv = gate wv). KEY CHANGE vs R8-R11: h is broadcast via
// v_readlane (each wave computes h[0..63] redundantly, one per lane, in its
// gate phase -- so the FMA phase reads h from ITS OWN lanes, on its own
// SIMD's VALU). This removes BOTH h-LDS round-trips and the 4-wave LDS-pipe
// contention (R8: 64 b128 reads/step serialized on the shared DS pipe) from
// the serial chain. Only remaining LDS on the chain: the 1-float z exchange.
// Weights: 64 asm-def floats (R10-proven; early-clobber per R12 lesson);
// waves_per_eu(1,1) for the 132-VGPR budget (R11-proven resident).
// ---------------------------------------------------------------------------
#define WAVE_BARRIER()                                        \
  do {                                                        \
    asm volatile("s_waitcnt lgkmcnt(0)" ::: "memory");        \
    __builtin_amdgcn_sched_barrier(0);                        \
    __builtin_amdgcn_s_barrier();                             \
    __builtin_amdgcn_sched_barrier(0);                        \
  } while (0)

#define PLOAD(dst, t_)                                                      \
  { const float* pp_ = zr + (size_t)(t_)*Gn + tid;                          \
    asm volatile("global_load_dword %0, %1, off" : "=v"(dst) : "v"(pp_)); }

// group g: rows 4g..4g+3 of Wh, this thread's column (early-clobbered defs)
#define DECLW(g)                                                            \
  float w##g##_0, w##g##_1, w##g##_2, w##g##_3;                             \
  { const float* pg_ = wh + (size_t)(4*(g))*Gn + tid;                       \
    asm volatile("global_load_dword %0, %4, off\n\t"                        \
                 "global_load_dword %1, %4, off offset:1024\n\t"            \
                 "global_load_dword %2, %4, off offset:2048\n\t"            \
                 "global_load_dword %3, %4, off offset:3072"                \
                 : "=&v"(w##g##_0), "=&v"(w##g##_1),                        \
                   "=&v"(w##g##_2), "=&v"(w##g##_3)                         \
                 : "v"(pg_)); }

// readlane h-broadcast: h[k] pulled from lane k of THIS wave (no LDS)
#define RLF(k) __int_as_float(__builtin_amdgcn_readlane(__float_as_int(h), (k)))

#define FMAK(g)                                                             \
  { A0 = fmaf(RLF(4*(g)+0), w##g##_0, A0);                                  \
    A1 = fmaf(RLF(4*(g)+1), w##g##_1, A1);                                  \
    A2 = fmaf(RLF(4*(g)+2), w##g##_2, A2);                                  \
    A3 = fmaf(RLF(4*(g)+3), w##g##_3, A3); }

template<bool IS_B0>
__global__ __attribute__((amdgpu_flat_work_group_size(256, 256),
                          amdgpu_waves_per_eu(1, 1)))
void lstm_fast(
    const int* __restrict__ x, const float* __restrict__ z,
    const float* __restrict__ wh, float* __restrict__ hb0,
    const float* __restrict__ dw, const float* __restrict__ db,
    float* __restrict__ out)
{
  const int b   = blockIdx.x;
  const int tid = threadIdx.x;
  const int wv  = tid >> 6;
  const int l   = tid & 63;

  __shared__ __align__(16) float z_s[2][Gn];
  __shared__ float sm[2][32];
  __shared__ int slen;

  if (tid == 0) slen = 0;
  __syncthreads();
  {
    int m0 = x[b*3*Tn + 2*Tn + tid];
    int m1 = x[b*3*Tn + 2*Tn + 256 + tid];
    atomicAdd(&slen, m0 + m1);
  }
  __syncthreads();
  const int len = slen;             // in [T/4, T]; mask is 1s then 0s

  const float* zr   = z   + (size_t)b*Tn*Gn;
  float*       hout = hb0 + (size_t)b*Tn*Hn;
  float c = 0.f, h = 0.f;          // lane l holds h[l]; redundant per wave

  if (IS_B0) {
    // rows [len, T-1] of hout must be 0 (ZX1 gemm reads all rows)
    for (int r = len + (tid >> 4); r < Tn; r += 16)
      *reinterpret_cast<float4*>(&hout[(size_t)r*Hn + (tid & 15)*4]) =
          make_float4(0.f, 0.f, 0.f, 0.f);
  }

  // 64 weight floats as early-clobbered asm defs -> VGPR residency
  DECLW(0)  DECLW(1)  DECLW(2)  DECLW(3)
  DECLW(4)  DECLW(5)  DECLW(6)  DECLW(7)
  DECLW(8)  DECLW(9)  DECLW(10) DECLW(11)
  DECLW(12) DECLW(13) DECLW(14) DECLW(15)

  // depth-4 z prefetch into fixed named regs
  float zp0, zp1, zp2, zp3;
  PLOAD(zp0, IS_B0 ? len-1 : Tn-len);
  PLOAD(zp1, IS_B0 ? len-2 : Tn-len+1);
  PLOAD(zp2, IS_B0 ? len-3 : Tn-len+2);
  PLOAD(zp3, IS_B0 ? len-4 : Tn-len+3);
  // drain weights + prologue z + zero-fill stores ONCE
  asm volatile("s_waitcnt vmcnt(0)" ::: "memory");
  __builtin_amdgcn_sched_barrier(0);

#define STEP(s_, ZREG)                                                       \
  {                                                                          \
    if (IS_B0) asm volatile("s_waitcnt vmcnt(7)" ::: "memory");              \
    else       asm volatile("s_waitcnt vmcnt(3)" ::: "memory");              \
    __builtin_amdgcn_sched_barrier(0);                                       \
    float A0 = ZREG, A1 = 0.f, A2 = 0.f, A3 = 0.f;                           \
    FMAK(0)  FMAK(1)  FMAK(2)  FMAK(3)                                       \
    FMAK(4)  FMAK(5)  FMAK(6)  FMAK(7)                                       \
    FMAK(8)  FMAK(9)  FMAK(10) FMAK(11)                                      \
    FMAK(12) FMAK(13) FMAK(14) FMAK(15)                                      \
    z_s[(s_)&1][tid] = (A0+A1)+(A2+A3);                                      \
    { /* issue load for step s_+4 early (max slack) */                       \
      int tn_ = IS_B0 ? (len-5-(s_)) : (Tn-len+(s_)+4);                      \
      tn_ = tn_ < 0 ? 0 : (tn_ > Tn-1 ? Tn-1 : tn_);                         \
      const float* pp_ = zr + (size_t)tn_*Gn + tid;                          \
      asm volatile("global_load_dword %0, %1, off" : "=v"(ZREG) : "v"(pp_)); \
    }                                                                        \
    WAVE_BARRIER();                                                          \
    float g0 = z_s[(s_)&1][l],      g1 = z_s[(s_)&1][Hn+l];                  \
    float g2 = z_s[(s_)&1][2*Hn+l], g3 = z_s[(s_)&1][3*Hn+l];                \
    float ig = sigf(g0), fg = sigf(g1);                                      \
    float gg = tanhfast(g2), og = sigf(g3);                                  \
    float cn_ = fmaf(fg, c, ig*gg);                                          \
    float hn_ = og * tanhfast(cn_);                                          \
    bool act_ = (s_) < len;                                                  \
    c = act_ ? cn_ : c;                                                      \
    h = act_ ? hn_ : h;                                                      \
    if (IS_B0 && wv == 0) {                                                  \
      int ts_ = len-1-(s_); ts_ = ts_ < 0 ? 0 : ts_;                         \
      float* sp_ = hout + (size_t)ts_*Hn + l;                                \
      asm volatile("global_store_dword %0, %1, off" :: "v"(sp_), "v"(h));    \
    }                                                                        \
  }

  const int lenr = (len + 3) & ~3;
  for (int s = 0; s < lenr; s += 4) {
    STEP(s+0, zp0);
    STEP(s+1, zp1);
    STEP(s+2, zp2);
    STEP(s+3, zp3);
  }
#undef STEP

  // drain asm VMEM; keep async-written regs alive past the drain (R5 lesson)
  asm volatile("s_waitcnt vmcnt(0)" ::: "memory");
  asm volatile("" :: "v"(zp0), "v"(zp1), "v"(zp2), "v"(zp3));
  __builtin_amdgcn_sched_barrier(0);

  if (!IS_B0) {
    // head: logits (C=20) + softmax; wave-0 lanes (h in-register via readlane)
    if (tid < Cn) {
      float lg = db[tid];
      #pragma unroll
      for (int k = 0; k < Hn; ++k) lg = fmaf(RLF(k), dw[k*Cn + tid], lg);
      sm[0][tid] = lg;
    }
    if (tid < Cn) {
      float m = sm[0][0];
      #pragma unroll
      for (int k = 1; k < Cn; ++k) m = fmaxf(m, sm[0][k]);
      float e = __expf(sm[0][tid] - m);
      sm[1][tid] = e;
      float ssum = 0.f;
      #pragma unroll
      for (int k = 0; k < Cn; ++k) ssum += sm[1][k];
      out[b*Cn + tid] = e / ssum;
    }
  }
}

// ---------------------------------------------------------------------------
extern "C" void kernel_launch(void* const* d_in, const int* in_sizes, int n_in,
                              void* d_out, int out_size, void* d_ws, size_t ws_size,
                              hipStream_t stream)
{
  const int*   x        = (const int*)  d_in[0];
  const float* word_emb = (const float*)d_in[1];
  const float* pos_emb  = (const float*)d_in[2];
  // forward-branch weights d_in[3..8] are dead code in the reference
  const float* wx_b0    = (const float*)d_in[9];
  const float* wh_b0    = (const float*)d_in[10];
  const float* b_b0     = (const float*)d_in[11];
  const float* wx_b1    = (const float*)d_in[12];
  const float* wh_b1    = (const float*)d_in[13];
  const float* b_b1     = (const float*)d_in[14];
  const float* dw       = (const float*)d_in[15];
  const float* db       = (const float*)d_in[16];
  float* out = (float*)d_out;

  float* z0  = (float*)d_ws;                    // B*T*256 f32 = 32 MiB (reused as ZX1)
  float* hb0 = z0 + (size_t)Bn*Tn*Gn;           // B*T*64  f32 =  8 MiB

  emb_proj_kernel<<<dim3((Bn*Tn)/64), dim3(256), 0, stream>>>(
      x, word_emb, pos_emb, wx_b0, b_b0, z0);
  lstm_fast<true><<<dim3(Bn), dim3(256), 0, stream>>>(
      x, z0, wh_b0, hb0, nullptr, nullptr, nullptr);
  zx1_gemm_kernel<<<dim3((Bn*Tn)/64), dim3(256), 0, stream>>>(
      hb0, wx_b1, b_b1, z0);                    // z0 buffer reused as ZX1
  lstm_fast<false><<<dim3(Bn), dim3(256), 0, stream>>>(
      x, z0, wh_b1, hb0, dw, db, out);
}

// Round 16
// 581.563 us; speedup vs baseline: 1.1602x; 1.1602x over previous
//
#include <hip/hip_runtime.h>
#include <hip/hip_bf16.h>
#include <hip/hip_fp16.h>

#define Bn 64
#define Tn 512
#define En 128
#define Hn 64
#define Gn 256   // 4*H
#define Cn 20

__device__ __forceinline__ float sigf(float x)      { return 1.f/(1.f+__expf(-x)); }
__device__ __forceinline__ float tanhfast(float x)  { return 2.f/(1.f+__expf(-2.f*x)) - 1.f; }

// ---------------------------------------------------------------------------
// Kernel A: Z0[b*T+t][j] = (word_emb[ids[b,t]] + pos_emb[t]) @ Wx_b0 + b_b0
// ---------------------------------------------------------------------------
__global__ __launch_bounds__(256, 1) void emb_proj_kernel(
    const int* __restrict__ x, const float* __restrict__ word_emb,
    const float* __restrict__ pos_emb, const float* __restrict__ wx,
    const float* __restrict__ bias, float* __restrict__ z0)
{
  __shared__ float emb[64][En];     // 32 KB
  __shared__ float wxl[32][Gn];     // 32 KB
  const int tid  = threadIdx.x;
  const int row0 = blockIdx.x * 64;

  #pragma unroll
  for (int it = 0; it < 8; ++it) {
    int idx = it*256 + tid;
    int rr  = idx >> 5;
    int e4  = (idx & 31) << 2;
    int r   = row0 + rr;
    int b   = r >> 9;
    int t   = r & (Tn-1);
    int id  = x[b*3*Tn + t];
    float4 we = *reinterpret_cast<const float4*>(&word_emb[(size_t)id*En + e4]);
    float4 pe = *reinterpret_cast<const float4*>(&pos_emb[(size_t)t*En + e4]);
    *reinterpret_cast<float4*>(&emb[rr][e4]) =
        make_float4(we.x+pe.x, we.y+pe.y, we.z+pe.z, we.w+pe.w);
  }

  const int jc = tid & 63;
  const int rg = tid >> 6;
  float acc[16][4];
  float4 bb = *reinterpret_cast<const float4*>(&bias[jc*4]);
  #pragma unroll
  for (int r = 0; r < 16; ++r) { acc[r][0]=bb.x; acc[r][1]=bb.y; acc[r][2]=bb.z; acc[r][3]=bb.w; }

  for (int ec = 0; ec < 4; ++ec) {
    __syncthreads();
    #pragma unroll
    for (int it = 0; it < 8; ++it) {
      int idx = it*256 + tid;
      int ee  = idx >> 6;
      int j4  = (idx & 63) << 2;
      *reinterpret_cast<float4*>(&wxl[ee][j4]) =
          *reinterpret_cast<const float4*>(&wx[(size_t)(ec*32+ee)*Gn + j4]);
    }
    __syncthreads();
    for (int ee = 0; ee < 32; ++ee) {
      float4 w = *reinterpret_cast<const float4*>(&wxl[ee][jc*4]);
      #pragma unroll
      for (int r = 0; r < 16; ++r) {
        float xv = emb[rg*16+r][ec*32+ee];
        acc[r][0] = fmaf(xv, w.x, acc[r][0]);
        acc[r][1] = fmaf(xv, w.y, acc[r][1]);
        acc[r][2] = fmaf(xv, w.z, acc[r][2]);
        acc[r][3] = fmaf(xv, w.w, acc[r][3]);
      }
    }
  }
  #pragma unroll
  for (int r = 0; r < 16; ++r) {
    size_t row = (size_t)row0 + rg*16 + r;
    *reinterpret_cast<float4*>(&z0[row*Gn + jc*4]) =
        make_float4(acc[r][0], acc[r][1], acc[r][2], acc[r][3]);
  }
}

// ---------------------------------------------------------------------------
// Kernel A2: ZX1[b*T+t][j] = hb0[b,t,:] @ Wx_b1 + b_b1
// ---------------------------------------------------------------------------
__global__ __launch_bounds__(256, 1) void zx1_gemm_kernel(
    const float* __restrict__ hb0, const float* __restrict__ wx,
    const float* __restrict__ bias, float* __restrict__ zx1)
{
  __shared__ float xl[64][Hn];
  __shared__ float wl[32][Gn];
  const int tid  = threadIdx.x;
  const int row0 = blockIdx.x * 64;

  #pragma unroll
  for (int it = 0; it < 4; ++it) {
    int idx = it*256 + tid;
    int rr  = idx >> 4;
    int e4  = (idx & 15) << 2;
    *reinterpret_cast<float4*>(&xl[rr][e4]) =
        *reinterpret_cast<const float4*>(&hb0[((size_t)row0+rr)*Hn + e4]);
  }

  const int jc = tid & 63;
  const int rg = tid >> 6;
  float acc[16][4];
  float4 bb = *reinterpret_cast<const float4*>(&bias[jc*4]);
  #pragma unroll
  for (int r = 0; r < 16; ++r) { acc[r][0]=bb.x; acc[r][1]=bb.y; acc[r][2]=bb.z; acc[r][3]=bb.w; }

  for (int kc = 0; kc < 2; ++kc) {
    __syncthreads();
    #pragma unroll
    for (int it = 0; it < 8; ++it) {
      int idx = it*256 + tid;
      int kk  = idx >> 6;
      int j4  = (idx & 63) << 2;
      *reinterpret_cast<float4*>(&wl[kk][j4]) =
          *reinterpret_cast<const float4*>(&wx[(size_t)(kc*32+kk)*Gn + j4]);
    }
    __syncthreads();
    for (int kk = 0; kk < 32; ++kk) {
      float4 w = *reinterpret_cast<const float4*>(&wl[kk][jc*4]);
      #pragma unroll
      for (int r = 0; r < 16; ++r) {
        float xv = xl[rg*16+r][kc*32+kk];
        acc[r][0] = fmaf(xv, w.x, acc[r][0]);
        acc[r][1] = fmaf(xv, w.y, acc[r][1]);
        acc[r][2] = fmaf(xv, w.z, acc[r][2]);
        acc[r][3] = fmaf(xv, w.w, acc[r][3]);
      }
    }
  }
  #pragma unroll
  for (int r = 0; r < 16; ++r) {
    size_t row = (size_t)row0 + rg*16 + r;
    *reinterpret_cast<float4*>(&zx1[row*Gn + jc*4]) =
        make_float4(acc[r][0], acc[r][1], acc[r][2], acc[r][3]);
  }
}

// ---------------------------------------------------------------------------
// Kernel A3: Wh fp32 [64][256] -> packed fp16-pair buffer uint[128][64]:
// wt16[(p*4+g)*64 + j] = pack( Wh[2p][64g+j], Wh[2p+1][64g+j] ).
// (low half = even k, high half = odd k -- matches v_dot2 operand order)
// ---------------------------------------------------------------------------
__global__ __launch_bounds__(256, 1) void wcvt_kernel(
    const float* __restrict__ wh, unsigned* __restrict__ wt16)
{
  int flat = blockIdx.x*256 + threadIdx.x;    // 0..8191
  int i = flat >> 6;                          // 0..127
  int j = flat & 63;
  int p = i >> 2;
  int g = i & 3;
  float w0 = wh[(size_t)(2*p)*Gn   + 64*g + j];
  float w1 = wh[(size_t)(2*p+1)*Gn + 64*g + j];
  unsigned lo = (unsigned)__half_as_ushort(__float2half(w0));
  unsigned hi = (unsigned)__half_as_ushort(__float2half(w1));
  wt16[flat] = lo | (hi << 16);
}

// ---------------------------------------------------------------------------
// Recurrence: ONE wave per batch element, NO barriers, NO cross-wave traffic.
// Lane l owns h-col l, c[l], and computes its own 4 gate columns
// {l, 64+l, 128+l, 192+l} via 128 v_dot2_f32_f16 (fp16 weight pairs packed
// in 128 dwords -- this halving is what makes the single-wave design fit
// the 256-VGPR cap that killed R13's fp32 version). h is exchanged via one
// wave-internal ds_write_b16 + 8 uniform b128 reads (in-order DS pipe, no
// sync needed). z and all gate math stay fp32. 16-round conclusion: the
// multi-wave z-exchange (write+lgkm+barrier+read ~600cy) was the invariant
// plateau; this removes it entirely.
// ---------------------------------------------------------------------------
#define DECLWD(p)                                                            \
  unsigned wI##p, wF##p, wG##p, wO##p;                                       \
  { const unsigned* pb_ = wt + (p)*256 + l;                                  \
    asm volatile("global_load_dword %0, %4, off\n\t"                         \
                 "global_load_dword %1, %4, off offset:256\n\t"              \
                 "global_load_dword %2, %4, off offset:512\n\t"              \
                 "global_load_dword %3, %4, off offset:768"                  \
                 : "=&v"(wI##p), "=&v"(wF##p), "=&v"(wG##p), "=&v"(wO##p)    \
                 : "v"(pb_)); }

#define DOTP(p, HU)                                                          \
  asm("v_dot2_f32_f16 %0, %1, %2, %0" : "+v"(aI) : "v"(HU), "v"(wI##p));    \
  asm("v_dot2_f32_f16 %0, %1, %2, %0" : "+v"(aF) : "v"(HU), "v"(wF##p));    \
  asm("v_dot2_f32_f16 %0, %1, %2, %0" : "+v"(aG) : "v"(HU), "v"(wG##p));    \
  asm("v_dot2_f32_f16 %0, %1, %2, %0" : "+v"(aO) : "v"(HU), "v"(wO##p));

#define ZLOAD4(ZI, ZF, ZG, ZO, t_)                                           \
  { const float* p_ = zr + (size_t)(t_)*Gn + l;                              \
    asm volatile("global_load_dword %0, %1, off"            : "=v"(ZI) : "v"(p_)); \
    asm volatile("global_load_dword %0, %1, off offset:256" : "=v"(ZF) : "v"(p_)); \
    asm volatile("global_load_dword %0, %1, off offset:512" : "=v"(ZG) : "v"(p_)); \
    asm volatile("global_load_dword %0, %1, off offset:768" : "=v"(ZO) : "v"(p_)); }

template<bool IS_B0>
__global__ __attribute__((amdgpu_flat_work_group_size(64, 64),
                          amdgpu_waves_per_eu(1, 1)))
void lstm_dot(
    const int* __restrict__ x, const float* __restrict__ z,
    const unsigned* __restrict__ wt, float* __restrict__ hb0,
    const float* __restrict__ dw, const float* __restrict__ db,
    float* __restrict__ out)
{
  const int b = blockIdx.x;
  const int l = threadIdx.x;        // 0..63, one wave
  __shared__ __align__(16) unsigned short hh[Hn];  // h as fp16, 128 B
  __shared__ float smh[Hn];
  __shared__ float sm0[32], sm1[32];

  // len = sum(mask) via per-lane partial + wave butterfly (mask 1s-then-0s)
  int msum = 0;
  #pragma unroll
  for (int i = 0; i < 8; ++i) msum += x[b*3*Tn + 2*Tn + i*64 + l];
  #pragma unroll
  for (int off = 1; off < 64; off <<= 1) msum += __shfl_xor(msum, off, 64);
  const int len = msum;             // in [128, 512]

  hh[l] = 0;                        // fp16 +0.0
  float c = 0.f, h = 0.f;
  const float* zr   = z   + (size_t)b*Tn*Gn;
  float*       hout = hb0 + (size_t)b*Tn*Hn;

  if (IS_B0) {
    // rows [len, T-1] of hout must be 0 (b1's inputs there are zeros)
    for (int r = len + (l >> 4); r < Tn; r += 4)
      *reinterpret_cast<float4*>(&hout[(size_t)r*Hn + (l & 15)*4]) =
          make_float4(0.f, 0.f, 0.f, 0.f);
  }

  // 128 packed weight dwords as early-clobbered asm defs (R10/R12-proven)
  DECLWD(0)  DECLWD(1)  DECLWD(2)  DECLWD(3)
  DECLWD(4)  DECLWD(5)  DECLWD(6)  DECLWD(7)
  DECLWD(8)  DECLWD(9)  DECLWD(10) DECLWD(11)
  DECLWD(12) DECLWD(13) DECLWD(14) DECLWD(15)
  DECLWD(16) DECLWD(17) DECLWD(18) DECLWD(19)
  DECLWD(20) DECLWD(21) DECLWD(22) DECLWD(23)
  DECLWD(24) DECLWD(25) DECLWD(26) DECLWD(27)
  DECLWD(28) DECLWD(29) DECLWD(30) DECLWD(31)

  // depth-2 z prefetch into named fp32 regs
  float zaI, zaF, zaG, zaO, zbI, zbF, zbG, zbO;
  ZLOAD4(zaI, zaF, zaG, zaO, IS_B0 ? len-1 : Tn-len);
  ZLOAD4(zbI, zbF, zbG, zbO, IS_B0 ? len-2 : Tn-len+1);
  // single prologue drain: weights + zero-fill + first 2 z rows
  asm volatile("s_waitcnt vmcnt(0)" ::: "memory");
  __builtin_amdgcn_sched_barrier(0);

#define STEP(s_, ZI, ZF, ZG, ZO)                                             \
  {                                                                          \
    if (IS_B0) asm volatile("s_waitcnt vmcnt(6)" ::: "memory");              \
    else       asm volatile("s_waitcnt vmcnt(4)" ::: "memory");              \
    __builtin_amdgcn_sched_barrier(0);                                       \
    float aI = ZI, aF = ZF, aG = ZG, aO = ZO;                                \
    { /* issue z loads for step s_+2 (max slack) */                          \
      int tn_ = IS_B0 ? (len-3-(s_)) : (Tn-len+(s_)+2);                      \
      tn_ = tn_ < 0 ? 0 : (tn_ > Tn-1 ? Tn-1 : tn_);                         \
      ZLOAD4(ZI, ZF, ZG, ZO, tn_);                                           \
    }                                                                        \
    { uint4 q = *reinterpret_cast<const uint4*>(&hh[0]);                     \
      DOTP(0,q.x)  DOTP(1,q.y)  DOTP(2,q.z)  DOTP(3,q.w) }                   \
    { uint4 q = *reinterpret_cast<const uint4*>(&hh[8]);                     \
      DOTP(4,q.x)  DOTP(5,q.y)  DOTP(6,q.z)  DOTP(7,q.w) }                   \
    { uint4 q = *reinterpret_cast<const uint4*>(&hh[16]);                    \
      DOTP(8,q.x)  DOTP(9,q.y)  DOTP(10,q.z) DOTP(11,q.w) }                  \
    { uint4 q = *reinterpret_cast<const uint4*>(&hh[24]);                    \
      DOTP(12,q.x) DOTP(13,q.y) DOTP(14,q.z) DOTP(15,q.w) }                  \
    { uint4 q = *reinterpret_cast<const uint4*>(&hh[32]);                    \
      DOTP(16,q.x) DOTP(17,q.y) DOTP(18,q.z) DOTP(19,q.w) }                  \
    { uint4 q = *reinterpret_cast<const uint4*>(&hh[40]);                    \
      DOTP(20,q.x) DOTP(21,q.y) DOTP(22,q.z) DOTP(23,q.w) }                  \
    { uint4 q = *reinterpret_cast<const uint4*>(&hh[48]);                    \
      DOTP(24,q.x) DOTP(25,q.y) DOTP(26,q.z) DOTP(27,q.w) }                  \
    { uint4 q = *reinterpret_cast<const uint4*>(&hh[56]);                    \
      DOTP(28,q.x) DOTP(29,q.y) DOTP(30,q.z) DOTP(31,q.w) }                  \
    float ig = sigf(aI), fg = sigf(aF);                                      \
    float gg = tanhfast(aG), og = sigf(aO);                                  \
    float cn_ = fmaf(fg, c, ig*gg);                                          \
    float hn_ = og * tanhfast(cn_);                                          \
    bool act_ = (s_) < len;                                                  \
    c = act_ ? cn_ : c;                                                      \
    h = act_ ? hn_ : h;                                                      \
    hh[l] = __half_as_ushort(__float2half(h));  /* wave-internal, in-order */\
    if (IS_B0) {                                                             \
      int ts_ = len-1-(s_); ts_ = ts_ < 0 ? 0 : ts_;                         \
      float* sp_ = hout + (size_t)ts_*Hn + l;                                \
      asm volatile("global_store_dword %0, %1, off" :: "v"(sp_), "v"(h));    \
    }                                                                        \
  }

  const int lenr = (len + 1) & ~1;
  for (int s = 0; s < lenr; s += 2) {
    STEP(s+0, zaI, zaF, zaG, zaO);
    STEP(s+1, zbI, zbF, zbG, zbO);
  }
#undef STEP

  // drain asm VMEM; keep async-written regs alive past the drain (R5 lesson)
  asm volatile("s_waitcnt vmcnt(0)" ::: "memory");
  asm volatile("" :: "v"(zaI), "v"(zaF), "v"(zaG), "v"(zaO),
                     "v"(zbI), "v"(zbF), "v"(zbG), "v"(zbO));
  __builtin_amdgcn_sched_barrier(0);

  if (!IS_B0) {
    // head: logits (C=20) + softmax; fp32 h via LDS, single wave in-order
    smh[l] = h;
    if (l < Cn) {
      float lg = db[l];
      #pragma unroll
      for (int k = 0; k < Hn; ++k) lg = fmaf(smh[k], dw[k*Cn + l], lg);
      sm0[l] = lg;
    }
    if (l < Cn) {
      float m = sm0[0];
      #pragma unroll
      for (int k = 1; k < Cn; ++k) m = fmaxf(m, sm0[k]);
      float e = __expf(sm0[l] - m);
      sm1[l] = e;
      float ssum = 0.f;
      #pragma unroll
      for (int k = 0; k < Cn; ++k) ssum += sm1[k];
      out[b*Cn + l] = e / ssum;
    }
  }
}

// ---------------------------------------------------------------------------
extern "C" void kernel_launch(void* const* d_in, const int* in_sizes, int n_in,
                              void* d_out, int out_size, void* d_ws, size_t ws_size,
                              hipStream_t stream)
{
  const int*   x        = (const int*)  d_in[0];
  const float* word_emb = (const float*)d_in[1];
  const float* pos_emb  = (const float*)d_in[2];
  // forward-branch weights d_in[3..8] are dead code in the reference
  const float* wx_b0    = (const float*)d_in[9];
  const float* wh_b0    = (const float*)d_in[10];
  const float* b_b0     = (const float*)d_in[11];
  const float* wx_b1    = (const float*)d_in[12];
  const float* wh_b1    = (const float*)d_in[13];
  const float* b_b1     = (const float*)d_in[14];
  const float* dw       = (const float*)d_in[15];
  const float* db       = (const float*)d_in[16];
  float* out = (float*)d_out;

  float*    z0   = (float*)d_ws;                     // B*T*256 f32 = 32 MiB (reused as ZX1)
  float*    hb0  = z0 + (size_t)Bn*Tn*Gn;            // B*T*64  f32 =  8 MiB
  unsigned* wt0  = (unsigned*)(hb0 + (size_t)Bn*Tn*Hn);  // 8192 u32 = 32 KiB
  unsigned* wt1  = wt0 + 128*64;                         // 8192 u32 = 32 KiB

  wcvt_kernel<<<dim3(32), dim3(256), 0, stream>>>(wh_b0, wt0);
  wcvt_kernel<<<dim3(32), dim3(256), 0, stream>>>(wh_b1, wt1);
  emb_proj_kernel<<<dim3((Bn*Tn)/64), dim3(256), 0, stream>>>(
      x, word_emb, pos_emb, wx_b0, b_b0, z0);
  lstm_dot<true><<<dim3(Bn), dim3(64), 0, stream>>>(
      x, z0, wt0, hb0, nullptr, nullptr, nullptr);
  zx1_gemm_kernel<<<dim3((Bn*Tn)/64), dim3(256), 0, stream>>>(
      hb0, wx_b1, b_b1, z0);                    // z0 buffer reused as ZX1
  lstm_dot<false><<<dim3(Bn), dim3(64), 0, stream>>>(
      x, z0, wt1, hb0, dw, db, out);
}